// Round 4
// baseline (3630.076 us; speedup 1.0000x reference)
//
#include <hip/hip_runtime.h>
#include <stdint.h>

// ============================================================================
// StochasticLSTMPredictor VRNN scan. B=256,T=512,I=128,H=256,L=64,HPR=50
// R4: occupancy/latency attack — 1024 threads/block (16 waves, 4/SIMD).
//  - per-thread work halves (~90 fdot2/step), dot chains split 16-way/8-way
//  - 74 weight u32/thread -> all true VGPRs (no AGPR round-trips)
//  - red16 via DPP (xor1, xor2, half_mirror 0x141, row_mirror 0x140)
//  - keeps R3 wins: lgkm-only barrier, hoisted z-independent dots, direct
//    global stores off the critical path
// ============================================================================

typedef _Float16 f16x2 __attribute__((ext_vector_type(2)));

__device__ __forceinline__ float bf2f(uint16_t u) {
  union { uint32_t u; float f; } c; c.u = ((uint32_t)u) << 16; return c.f;
}
__device__ __forceinline__ uint16_t f2bf(float f) {
  union { float f; uint32_t u; } c; c.f = f;
  uint32_t u = c.u;
  uint32_t r = (u + 0x7FFFu + ((u >> 16) & 1u)) >> 16;
  return (uint16_t)r;
}
__device__ __forceinline__ uint32_t packh2(float a, float b) {
  union { f16x2 h; uint32_t u; } c;
  c.h.x = (_Float16)a; c.h.y = (_Float16)b; return c.u;
}
__device__ __forceinline__ float fdot2(uint32_t a, uint32_t b, float c) {
  union { uint32_t u; f16x2 h; } ua, ub; ua.u = a; ub.u = b;
#if __has_builtin(__builtin_amdgcn_fdot2)
  return __builtin_amdgcn_fdot2(ua.h, ub.h, c, false);
#else
  return c + (float)ua.h.x * (float)ub.h.x + (float)ua.h.y * (float)ub.h.y;
#endif
}

// ---- DPP butterfly reductions (VALU pipe) ----
template <int CTRL>
__device__ __forceinline__ float dpp_mov(float x) {
#if __has_builtin(__builtin_amdgcn_update_dpp)
  union { float f; int i; } a, b;
  a.f = x;
  b.i = __builtin_amdgcn_update_dpp(0, a.i, CTRL, 0xF, 0xF, true);
  return b.f;
#else
  return __shfl_xor(x, 1);
#endif
}
__device__ __forceinline__ float red4(float x) {
  x += dpp_mov<0xB1>(x); x += dpp_mov<0x4E>(x); return x;
}
__device__ __forceinline__ float red8(float x) {
  x += dpp_mov<0xB1>(x); x += dpp_mov<0x4E>(x); x += dpp_mov<0x141>(x); return x;
}
__device__ __forceinline__ float red16(float x) {
  x += dpp_mov<0xB1>(x); x += dpp_mov<0x4E>(x);
  x += dpp_mov<0x141>(x); x += dpp_mov<0x140>(x); return x;
}

// LDS-only barrier: no vmcnt(0) drain
__device__ __forceinline__ void barrier_lds() {
  asm volatile("s_waitcnt lgkmcnt(0)\n\ts_barrier" ::: "memory");
}

// dtype sniff (harness test is bf16; reference f32 — support both)
__device__ __forceinline__ int sniff_bf16(const uint32_t* xw) {
  int cnt = 0;
#pragma unroll
  for (int i = 0; i < 64; ++i) {
    uint32_t e = (xw[i] >> 7) & 0xFFu;
    cnt += (e >= 0x70u && e <= 0x7Fu) ? 1 : 0;
  }
  return cnt >= 32;
}
__device__ __forceinline__ float loadIn(const void* p, size_t i, int isbf) {
  return isbf ? bf2f(((const uint16_t*)p)[i]) : ((const float*)p)[i];
}
__device__ __forceinline__ void storeOut(void* p, size_t i, float v, int isbf) {
  if (isbf) ((uint16_t*)p)[i] = f2bf(v);
  else      ((float*)p)[i] = v;
}

// ws layout (uint32 units):
// [0, 75776)     : 74 pairs x 1024 threads, SoA [pair][tid], f16x2
// [75776, 94208) : s_w2 image: qm2@0 ql2@2304 pm2@4608 pl2@6912 (64 rows x
//                  stride36), wh2@9216 (256 rows x stride36)
// [94208, 95168) : biases f32 (same as R3)
#define WS_W2   75776
#define WS_BIAS 94208
#define N_JOBS  95168

struct PrepArgs {
  const void* W[11]; // qm1 ql1 pm1 pl1 h1 wo qm2 ql2 pm2 pl2 h2
  const void* B[11]; // bqm1 bql1 bpm1 bpl1 bh1 bqm2 bql2 bpm2 bpl2 bh2 bo
  const uint32_t* xw;
};

__global__ void vrnn_prep(PrepArgs a, uint32_t* __restrict__ ws) {
  const int isbf = sniff_bf16(a.xw);
  int j = blockIdx.x * 256 + threadIdx.x;
  if (j < 75776) {
    int p = j >> 10, tid = j & 1023;
    int t16 = tid >> 4, c16 = tid & 15;
    int t8 = tid >> 3, c8 = tid & 7;
    const void* W; int row, k, K; bool valid;
    if (p < 12)       { W = a.W[0]; row = t16; k = c16*24 + p*2;          K = 384; valid = row < 50; }
    else if (p < 24)  { W = a.W[1]; row = t16; k = c16*24 + (p-12)*2;     K = 384; valid = row < 50; }
    else if (p < 32)  { W = a.W[2]; row = t16; k = c16*16 + (p-24)*2;     K = 256; valid = row < 50; }
    else if (p < 40)  { W = a.W[3]; row = t16; k = c16*16 + (p-32)*2;     K = 256; valid = row < 50; }
    else if (p < 52)  { W = a.W[4]; row = t16; k = c16*24 + (p-40)*2;     K = 448; valid = row < 50; }
    else if (p < 54)  { W = a.W[4]; row = t16; k = 384 + c16*4 + (p-52)*2; K = 448; valid = row < 50; }
    else if (p < 70)  { W = a.W[5]; row = t8;  k = c8*32 + (p-54)*2;      K = 320; valid = true; }
    else              { W = a.W[5]; row = t8;  k = 256 + c8*8 + (p-70)*2; K = 320; valid = true; }
    float f0 = valid ? loadIn(W, (size_t)row * K + k, isbf)     : 0.f;
    float f1 = valid ? loadIn(W, (size_t)row * K + k + 1, isbf) : 0.f;
    ws[j] = packh2(f0, f1);
  } else if (j < WS_BIAS) {
    int q = j - WS_W2;
    const void* W; int r, kp;
    if (q < 9216) { int m = q / 2304, rem = q % 2304; r = rem / 36; kp = rem % 36; W = a.W[6 + m]; }
    else          { int rem = q - 9216;               r = rem / 36; kp = rem % 36; W = a.W[10]; }
    uint32_t v = 0;
    if (kp < 25) v = packh2(loadIn(W, r * 50 + kp * 2, isbf),
                            loadIn(W, r * 50 + kp * 2 + 1, isbf));
    ws[j] = v;
  } else if (j < N_JOBS) {
    int q = j - WS_BIAS; float v = 0.f;
    if (q < 320)      { int m = q >> 6, i = q & 63; if (i < 50) v = loadIn(a.B[m], i, isbf); }
    else if (q < 576) { int m = (q - 320) >> 6;     v = loadIn(a.B[5 + m], q & 63, isbf); }
    else if (q < 832) { v = loadIn(a.B[9],  q - 576, isbf); }
    else              { v = loadIn(a.B[10], q - 832, isbf); }
    ((float*)ws)[j] = v;
  }
}

__global__ __launch_bounds__(1024, 4) void vrnn_main(
    const void* __restrict__ x, const void* __restrict__ hidden,
    const void* __restrict__ noise, const uint32_t* __restrict__ ws,
    void* __restrict__ out)
{
  __shared__ __align__(16) uint32_t s_w2[18432];
  __shared__ float s_bias[960];
  __shared__ __align__(16) _Float16 s_v[448];    // [x(128)|h(256)|z(64)]
  __shared__ __align__(16) uint32_t s_actu[180]; // qm@0 ql@36 pm@72 pl@108 ah@144 (u32 stride 36)
  _Float16* s_act = (_Float16*)s_actu;

  const int tid = threadIdx.x;
  const int b = blockIdx.x;
  const int isbf = sniff_bf16((const uint32_t*)x);

  // ---- register-resident weights, f16x2 pairs (74 u32/thread) ----
  uint32_t wqm1[12], wql1[12], wpm1[8], wpl1[8], wh1a[12], wh1z[2], woh[16], woz[4];
#pragma unroll
  for (int i = 0; i < 12; ++i) wqm1[i] = ws[(0  + i) * 1024 + tid];
#pragma unroll
  for (int i = 0; i < 12; ++i) wql1[i] = ws[(12 + i) * 1024 + tid];
#pragma unroll
  for (int i = 0; i < 8;  ++i) wpm1[i] = ws[(24 + i) * 1024 + tid];
#pragma unroll
  for (int i = 0; i < 8;  ++i) wpl1[i] = ws[(32 + i) * 1024 + tid];
#pragma unroll
  for (int i = 0; i < 12; ++i) wh1a[i] = ws[(40 + i) * 1024 + tid];
#pragma unroll
  for (int i = 0; i < 2;  ++i) wh1z[i] = ws[(52 + i) * 1024 + tid];
#pragma unroll
  for (int i = 0; i < 16; ++i) woh[i]  = ws[(54 + i) * 1024 + tid];
#pragma unroll
  for (int i = 0; i < 4;  ++i) woz[i]  = ws[(70 + i) * 1024 + tid];

  for (int i = tid; i < 18432; i += 1024) s_w2[i] = ws[WS_W2 + i];
  {
    const float* wsf = (const float*)(ws + WS_BIAS);
    if (tid < 960) s_bias[tid] = wsf[tid];
  }

  if (tid < 128)      s_v[tid] = (_Float16)loadIn(x, (size_t)b * 65536 + tid, isbf);
  else if (tid < 384) s_v[tid] = (_Float16)loadIn(hidden, (size_t)b * 256 + (tid - 128), isbf);
  else if (tid < 448) s_v[tid] = (_Float16)0.f;

  const int row16 = tid >> 4, c16 = tid & 15;
  const int i8 = tid >> 3, c8 = tid & 7;          // Wo rows / P2 dots
  const int r4 = tid >> 2, c4 = tid & 3;          // P4
  const uint4* v4 = (const uint4*)s_v;
  const uint32_t* s_vu = (const uint32_t*)s_v;

  float eps_r = 0.f;
  if (c8 == 0 && i8 < 64) eps_r = loadIn(noise, (size_t)b * 32768 + i8, isbf);
  float xnext = 0.f;

  __syncthreads();

  const size_t OFF_PMU = 16777216u;
  const size_t OFF_PLV = 25165824u;
  const size_t OFF_QMU = 33554432u;
  const size_t OFF_QLV = 41943040u;

#pragma unroll 1
  for (int t = 0; t < 512; ++t) {
    const size_t bt = (size_t)b * 512 + t;
    if (tid >= 896) {                              // prefetch x_{t+1}
      int tn = (t < 511) ? t + 1 : 511;
      xnext = loadIn(x, ((size_t)b * 512 + tn) * 128 + (tid - 896), isbf);
    }

    // ---- P1: all z-independent dots ----
    float a_qm = 0.f, a_ql = 0.f, a_hx = 0.f;
    {
      const int g = c16 * 3;                       // xh = v[0:384], 16 lanes/row
#pragma unroll
      for (int i = 0; i < 3; ++i) {
        uint4 q = v4[g + i];
        a_qm = fdot2(wqm1[4*i+0], q.x, a_qm); a_ql = fdot2(wql1[4*i+0], q.x, a_ql); a_hx = fdot2(wh1a[4*i+0], q.x, a_hx);
        a_qm = fdot2(wqm1[4*i+1], q.y, a_qm); a_ql = fdot2(wql1[4*i+1], q.y, a_ql); a_hx = fdot2(wh1a[4*i+1], q.y, a_hx);
        a_qm = fdot2(wqm1[4*i+2], q.z, a_qm); a_ql = fdot2(wql1[4*i+2], q.z, a_ql); a_hx = fdot2(wh1a[4*i+2], q.z, a_hx);
        a_qm = fdot2(wqm1[4*i+3], q.w, a_qm); a_ql = fdot2(wql1[4*i+3], q.w, a_ql); a_hx = fdot2(wh1a[4*i+3], q.w, a_hx);
      }
    }
    float a_pm = 0.f, a_pl = 0.f;
    {
      const int g = 16 + c16 * 2;                  // h = v[128:384], 16 lanes/row
#pragma unroll
      for (int i = 0; i < 2; ++i) {
        uint4 q = v4[g + i];
        a_pm = fdot2(wpm1[4*i+0], q.x, a_pm); a_pl = fdot2(wpl1[4*i+0], q.x, a_pl);
        a_pm = fdot2(wpm1[4*i+1], q.y, a_pm); a_pl = fdot2(wpl1[4*i+1], q.y, a_pl);
        a_pm = fdot2(wpm1[4*i+2], q.z, a_pm); a_pl = fdot2(wpl1[4*i+2], q.z, a_pl);
        a_pm = fdot2(wpm1[4*i+3], q.w, a_pm); a_pl = fdot2(wpl1[4*i+3], q.w, a_pl);
      }
    }
    float a_o = 0.f;
    {
      const int g = 16 + c8 * 4;                   // h, 8 lanes/row (128 rows)
#pragma unroll
      for (int i = 0; i < 4; ++i) {
        uint4 q = v4[g + i];
        a_o = fdot2(woh[4*i+0], q.x, a_o);
        a_o = fdot2(woh[4*i+1], q.y, a_o);
        a_o = fdot2(woh[4*i+2], q.z, a_o);
        a_o = fdot2(woh[4*i+3], q.w, a_o);
      }
    }
    a_qm = red16(a_qm); a_ql = red16(a_ql); a_pm = red16(a_pm); a_pl = red16(a_pl);
    if (c16 == 0) {
      s_act[row16]       = (_Float16)fmaxf(a_qm + s_bias[row16],       0.f);
      s_act[72 + row16]  = (_Float16)fmaxf(a_ql + s_bias[64 + row16],  0.f);
      s_act[144 + row16] = (_Float16)fmaxf(a_pm + s_bias[128 + row16], 0.f);
      s_act[216 + row16] = (_Float16)fmaxf(a_pl + s_bias[192 + row16], 0.f);
    }
    barrier_lds();

    // ---- P2: mu/lv (128 dots, 8 lanes/dot); z ----
    {
      const bool isq = i8 < 64;
      const int r = isq ? i8 : i8 - 64;
      const uint32_t* Wm = s_w2 + (isq ? 0 : 4608) + r * 36 + c8 * 4;
      const uint32_t* Wl = s_w2 + (isq ? 2304 : 6912) + r * 36 + c8 * 4;
      const uint32_t* am = s_actu + (isq ? 0 : 72) + c8 * 4;
      const uint32_t* al = s_actu + (isq ? 36 : 108) + c8 * 4;
      uint4 wm = *(const uint4*)Wm, wl = *(const uint4*)Wl;
      uint4 vm = *(const uint4*)am, vl = *(const uint4*)al;
      float mu = 0.f, lv = 0.f;
      mu = fdot2(wm.x, vm.x, mu); lv = fdot2(wl.x, vl.x, lv);
      mu = fdot2(wm.y, vm.y, mu); lv = fdot2(wl.y, vl.y, lv);
      mu = fdot2(wm.z, vm.z, mu); lv = fdot2(wl.z, vl.z, lv);
      mu = fdot2(wm.w, vm.w, mu); lv = fdot2(wl.w, vl.w, lv);
      mu = red8(mu); lv = red8(lv);
      if (c8 == 0) {
        mu += s_bias[(isq ? 320 : 448) + r];
        lv += s_bias[(isq ? 384 : 512) + r];
        storeOut(out, (isq ? OFF_QMU : OFF_PMU) + bt * 64 + r, mu, isbf);
        storeOut(out, (isq ? OFF_QLV : OFF_PLV) + bt * 64 + r, lv, isbf);
        if (isq) {
          float z = mu + __expf(0.5f * lv) * eps_r;
          s_v[384 + r] = (_Float16)z;
          int tn = (t < 511) ? t + 1 : 511;
          eps_r = loadIn(noise, ((size_t)b * 512 + tn) * 64 + r, isbf);
        }
      }
    }
    barrier_lds();

    // ---- P3: z-only completions; x_hat straight to global ----
    {
      uint4 qz = v4[48 + c8];                      // z chunk for Wo lanes
      float o = a_o;
      o = fdot2(woz[0], qz.x, o);
      o = fdot2(woz[1], qz.y, o);
      o = fdot2(woz[2], qz.z, o);
      o = fdot2(woz[3], qz.w, o);
      uint32_t z0 = s_vu[192 + c16 * 2], z1 = s_vu[193 + c16 * 2];
      float ah = a_hx;
      ah = fdot2(wh1z[0], z0, ah);
      ah = fdot2(wh1z[1], z1, ah);
      o = red8(o); ah = red16(ah);
      if (c8 == 0) {
        float s0 = 1.f / (1.f + __expf(-(o + s_bias[832 + i8])));
        storeOut(out, bt * 128 + i8, s0, isbf);
      }
      if (c16 == 0)
        s_act[288 + row16] = (_Float16)fmaxf(ah + s_bias[256 + row16], 0.f);
    }
    barrier_lds();

    // ---- P4: h-update (256 rows, 4 lanes/row); commit x_{t+1} ----
    {
      const uint32_t* Wr = s_w2 + 9216 + r4 * 36 + c4 * 8;
      const uint32_t* ap = s_actu + 144 + c4 * 8;
      uint4 w0 = *(const uint4*)Wr, w1 = *(const uint4*)(Wr + 4);
      uint4 a0 = *(const uint4*)ap, a1 = *(const uint4*)(ap + 4);
      float h0 = 0.f, h1 = 0.f;
      h0 = fdot2(w0.x, a0.x, h0); h1 = fdot2(w1.x, a1.x, h1);
      h0 = fdot2(w0.y, a0.y, h0); h1 = fdot2(w1.y, a1.y, h1);
      h0 = fdot2(w0.z, a0.z, h0); h1 = fdot2(w1.z, a1.z, h1);
      h0 = fdot2(w0.w, a0.w, h0); h1 = fdot2(w1.w, a1.w, h1);
      float hh = red4(h0 + h1);
      if (c4 == 0) s_v[128 + r4] = (_Float16)(hh + s_bias[576 + r4]);
    }
    if (tid >= 896) s_v[tid - 896] = (_Float16)xnext;
    barrier_lds();
  }
}

extern "C" void kernel_launch(void* const* d_in, const int* in_sizes, int n_in,
                              void* d_out, int out_size, void* d_ws, size_t ws_size,
                              hipStream_t stream) {
  (void)in_sizes; (void)n_in; (void)out_size; (void)ws_size;
  PrepArgs a;
  a.W[0]  = d_in[11]; // Wqm1 [50,384]
  a.W[1]  = d_in[15]; // Wql1 [50,384]
  a.W[2]  = d_in[3];  // Wpm1 [50,256]
  a.W[3]  = d_in[7];  // Wpl1 [50,256]
  a.W[4]  = d_in[19]; // Wh1  [50,448]
  a.W[5]  = d_in[23]; // Wo   [128,320]
  a.W[6]  = d_in[13]; // Wqm2 [64,50]
  a.W[7]  = d_in[17]; // Wql2 [64,50]
  a.W[8]  = d_in[5];  // Wpm2 [64,50]
  a.W[9]  = d_in[9];  // Wpl2 [64,50]
  a.W[10] = d_in[21]; // Wh2  [256,50]
  a.B[0]  = d_in[12]; // bqm1
  a.B[1]  = d_in[16]; // bql1
  a.B[2]  = d_in[4];  // bpm1
  a.B[3]  = d_in[8];  // bpl1
  a.B[4]  = d_in[20]; // bh1
  a.B[5]  = d_in[14]; // bqm2
  a.B[6]  = d_in[18]; // bql2
  a.B[7]  = d_in[6];  // bpm2
  a.B[8]  = d_in[10]; // bpl2
  a.B[9]  = d_in[22]; // bh2
  a.B[10] = d_in[24]; // bo
  a.xw    = (const uint32_t*)d_in[0];

  uint32_t* ws = (uint32_t*)d_ws;
  vrnn_prep<<<dim3((N_JOBS + 255) / 256), dim3(256), 0, stream>>>(a, ws);
  vrnn_main<<<dim3(256), dim3(1024), 0, stream>>>(d_in[0], d_in[1], d_in[2], ws, d_out);
}